// Round 1
// baseline (6047.767 us; speedup 1.0000x reference)
//
#include <hip/hip_runtime.h>

#define B 4
#define N 8192
#define F 64
#define S 2048
#define K 16
#define C 128
#define R (B*S*K)   // 131072 rows

// ---------- exact-arithmetic helpers (match numpy op order, no fma fusion) ----------
__device__ __forceinline__ float dist2_sub(float ax, float ay, float az,
                                           float bx, float by, float bz) {
#pragma clang fp contract(off)
  float dx = ax - bx, dy = ay - by, dz = az - bz;
  return (dx*dx + dy*dy) + dz*dz;          // ((d0+d1)+d2), separate rounding
}

__device__ __forceinline__ float norm2f(float x, float y, float z) {
#pragma clang fp contract(off)
  return (x*x + y*y) + z*z;
}

__device__ __forceinline__ float knn_d2(float4 q, float4 p) {
#pragma clang fp contract(off)
  float dot = (q.x*p.x + q.y*p.y) + q.z*p.z;
  return (q.w + p.w) - 2.0f*dot;           // (qn+pn) - 2*dot, reference order
}

// ---------- prep: pad xyz to float4 with |p|^2 in w ----------
__global__ void prep_kernel(const float* __restrict__ xyz, float4* __restrict__ pts4) {
  int i = blockIdx.x*blockDim.x + threadIdx.x;   // B*N
  if (i >= B*N) return;
  float x = xyz[i*3+0], y = xyz[i*3+1], z = xyz[i*3+2];
  pts4[i] = make_float4(x, y, z, norm2f(x, y, z));
}

// ---------- FPS: one block per batch, 256 threads x 32 points in registers ----------
__global__ __launch_bounds__(256, 1) void fps_kernel(const float4* __restrict__ pts4,
                                                     float4* __restrict__ q4,
                                                     float* __restrict__ out_xyz) {
  const int b = blockIdx.x;
  const int t = threadIdx.x;
  const float4* pb = pts4 + b*N;

  float px[32], py[32], pz[32], md[32];
#pragma unroll
  for (int i = 0; i < 32; ++i) {
    float4 v = pb[i*256 + t];           // strided: coalesced, ascending global idx per thread
    px[i] = v.x; py[i] = v.y; pz[i] = v.z; md[i] = 1e10f;   // BIG
  }

  __shared__ float lv[2][4];
  __shared__ int   li[2][4];

  int w = 0;                            // reference starts at index 0
  for (int s = 0; ; ++s) {
    w = __builtin_amdgcn_readfirstlane(w);
    float4 pw = pb[w];                  // uniform -> scalar load
    if (t == 0) {
      q4[b*S + s] = pw;
      out_xyz[(b*S + s)*3 + 0] = pw.x;
      out_xyz[(b*S + s)*3 + 1] = pw.y;
      out_xyz[(b*S + s)*3 + 2] = pw.z;
    }
    if (s == S-1) break;

    float bv = -1.0f; int bi = 0;
#pragma unroll
    for (int i = 0; i < 32; ++i) {
      float d = dist2_sub(px[i], py[i], pz[i], pw.x, pw.y, pw.z);
      float m = fminf(md[i], d);
      md[i] = m;
      bool g = m > bv;                  // strict >, ascending index: first max kept
      bv = g ? m : bv;
      bi = g ? (i*256 + t) : bi;
    }
    // wave butterfly reduce, tie -> lowest index
#pragma unroll
    for (int off = 32; off >= 1; off >>= 1) {
      float ov = __shfl_xor(bv, off, 64);
      int   oi = __shfl_xor(bi, off, 64);
      if (ov > bv || (ov == bv && oi < bi)) { bv = ov; bi = oi; }
    }
    int par = s & 1;
    int wid = t >> 6;
    if ((t & 63) == 0) { lv[par][wid] = bv; li[par][wid] = bi; }
    __syncthreads();
    float fv = lv[par][0]; int fi = li[par][0];
#pragma unroll
    for (int j = 1; j < 4; ++j) {
      float ov = lv[par][j]; int oi = li[par][j];
      if (ov > fv || (ov == fv && oi < fi)) { fv = ov; fi = oi; }
    }
    w = fi;
  }
}

// ---------- KNN: one thread per query, full scan, sorted 16-reg insertion ----------
__global__ __launch_bounds__(256, 1) void knn_kernel(const float4* __restrict__ pts4,
                                                     const float4* __restrict__ q4,
                                                     int* __restrict__ knn) {
  int qi = blockIdx.x*256 + threadIdx.x;   // 0..B*S-1
  int b = qi >> 11;                        // S = 2048
  const float4* pb = pts4 + b*N;
  float4 q = q4[qi];

  float dv[16]; int di[16];
#pragma unroll
  for (int j = 0; j < 16; ++j) { dv[j] = 3.4e38f; di[j] = 0; }

  for (int n = 0; n < N; ++n) {
    float4 p = pb[n];                      // uniform across wave -> scalar load
    float d2 = knn_d2(q, p);
    if (d2 < dv[15]) {                     // strict: incumbent (earlier index) wins ties
#pragma unroll
      for (int j = 15; j >= 1; --j) {
        bool c1 = d2 < dv[j-1];
        bool c2 = d2 < dv[j];
        dv[j] = c1 ? dv[j-1] : (c2 ? d2 : dv[j]);
        di[j] = c1 ? di[j-1] : (c2 ? n  : di[j]);
      }
      if (d2 < dv[0]) { dv[0] = d2; di[0] = n; }
    }
  }
#pragma unroll
  for (int j = 0; j < 16; ++j) knn[qi*16 + j] = di[j];
}

// ---------- GEMM0: gather row (3 xyz-norm + 64 feat) and multiply by w0 [128x67] ----------
__global__ __launch_bounds__(256, 2) void gemm0_kernel(const float4* __restrict__ pts4,
                                                       const float4* __restrict__ q4,
                                                       const float* __restrict__ feat,
                                                       const int* __restrict__ knn,
                                                       const float* __restrict__ w0,
                                                       const float* __restrict__ b0,
                                                       float* __restrict__ Z) {
  int r = blockIdx.x*256 + threadIdx.x;    // 0..R-1
  int bs = r >> 4;                         // b*S + s
  int b  = r >> 15;                        // S*K = 32768 rows per batch
  int p  = knn[r];
  float4 q  = q4[bs];
  float4 pp = pts4[b*N + p];

  float row[67];
  row[0] = pp.x - q.x; row[1] = pp.y - q.y; row[2] = pp.z - q.z;
  const float4* fp = (const float4*)(feat + (size_t)(b*N + p)*F);
#pragma unroll
  for (int i = 0; i < 16; ++i) {
    float4 v = fp[i];
    row[3+4*i] = v.x; row[4+4*i] = v.y; row[5+4*i] = v.z; row[6+4*i] = v.w;
  }

  float* zr = Z + (size_t)r*C;
  for (int og = 0; og < C/4; ++og) {
    float a0 = b0[og*4+0], a1 = b0[og*4+1], a2 = b0[og*4+2], a3 = b0[og*4+3];
    const float* wr = w0 + og*4*67;        // uniform -> scalar loads
#pragma unroll
    for (int c = 0; c < 67; ++c) {
      float x = row[c];
      a0 = fmaf(x, wr[c      ], a0);
      a1 = fmaf(x, wr[67  + c], a1);
      a2 = fmaf(x, wr[134 + c], a2);
      a3 = fmaf(x, wr[201 + c], a3);
    }
    ((float4*)zr)[og] = make_float4(a0, a1, a2, a3);
  }
}

// ---------- per-channel stats partials: sum and sumsq over rows ----------
__global__ void stats_kernel(const float* __restrict__ Z, float* __restrict__ part) {
  int c = threadIdx.x & 127;
  int g = threadIdx.x >> 7;                // 0/1
  int chunk = blockIdx.x*2 + g;            // 0..255
  const int rows = R/256;                  // 512
  const float* zp = Z + (size_t)chunk*rows*C + c;
  float s1 = 0.f, s2 = 0.f;
  for (int j = 0; j < rows; ++j) {
    float v = zp[(size_t)j*C];
    s1 += v;
    s2 = fmaf(v, v, s2);
  }
  __shared__ float sh[2][2][128];
  sh[g][0][c] = s1; sh[g][1][c] = s2;
  __syncthreads();
  if (g == 0) {
    part[(blockIdx.x*128 + c)*2 + 0] = s1 + sh[1][0][c];
    part[(blockIdx.x*128 + c)*2 + 1] = s2 + sh[1][1][c];
  }
}

// ---------- finalize BN: A = gamma*rstd, B = beta - mean*gamma*rstd ----------
__global__ void finalize_kernel(const float* __restrict__ part,
                                const float* __restrict__ gamma,
                                const float* __restrict__ beta,
                                float* __restrict__ AB) {
  int c = threadIdx.x;                     // 128 threads
  float s1 = 0.f, s2 = 0.f;
  for (int i = 0; i < 128; ++i) {
    s1 += part[(i*128 + c)*2 + 0];
    s2 += part[(i*128 + c)*2 + 1];
  }
  const float inv = 1.0f/(float)R;
  float mean = s1*inv;
  float var  = s2*inv - mean*mean;         // biased variance
  float rstd = rsqrtf(var + 1e-5f);
  float a = gamma[c]*rstd;
  AB[c]     = a;
  AB[C + c] = beta[c] - mean*a;
}

// ---------- GEMM1: in-place on Z; applies BN0+ReLU on load ----------
__global__ __launch_bounds__(256, 2) void gemm1_kernel(float* __restrict__ Z,
                                                       const float* __restrict__ AB0,
                                                       const float* __restrict__ w1,
                                                       const float* __restrict__ b1) {
  int r = blockIdx.x*256 + threadIdx.x;
  float* zr = Z + (size_t)r*C;
  float h[C];
#pragma unroll
  for (int i = 0; i < C/4; ++i) {
    float4 v = ((const float4*)zr)[i];
    h[4*i+0] = fmaxf(fmaf(v.x, AB0[4*i+0], AB0[C+4*i+0]), 0.f);
    h[4*i+1] = fmaxf(fmaf(v.y, AB0[4*i+1], AB0[C+4*i+1]), 0.f);
    h[4*i+2] = fmaxf(fmaf(v.z, AB0[4*i+2], AB0[C+4*i+2]), 0.f);
    h[4*i+3] = fmaxf(fmaf(v.w, AB0[4*i+3], AB0[C+4*i+3]), 0.f);
  }
  for (int og = 0; og < C/4; ++og) {
    float a0 = b1[og*4+0], a1 = b1[og*4+1], a2 = b1[og*4+2], a3 = b1[og*4+3];
    const float* wr = w1 + og*4*C;         // uniform -> scalar loads
#pragma unroll
    for (int c = 0; c < C; ++c) {
      float x = h[c];
      a0 = fmaf(x, wr[c      ], a0);
      a1 = fmaf(x, wr[C   + c], a1);
      a2 = fmaf(x, wr[2*C + c], a2);
      a3 = fmaf(x, wr[3*C + c], a3);
    }
    ((float4*)zr)[og] = make_float4(a0, a1, a2, a3);   // safe: h fully read
  }
}

// ---------- maxpool over K with BN1+ReLU fused ----------
__global__ void maxpool_kernel(const float* __restrict__ Z,
                               const float* __restrict__ AB1,
                               float* __restrict__ outF) {
  int t = blockIdx.x*256 + threadIdx.x;    // B*S*32
  int bs = t >> 5, c4 = t & 31;
  const float4* zp = (const float4*)Z + (size_t)bs*K*(C/4) + c4;
  float4 A  = ((const float4*)AB1)[c4];
  float4 Bb = ((const float4*)(AB1 + C))[c4];
  float4 m = make_float4(-3.4e38f, -3.4e38f, -3.4e38f, -3.4e38f);
#pragma unroll
  for (int k = 0; k < K; ++k) {
    float4 z = zp[(size_t)k*(C/4)];
    m.x = fmaxf(m.x, fmaf(z.x, A.x, Bb.x));
    m.y = fmaxf(m.y, fmaf(z.y, A.y, Bb.y));
    m.z = fmaxf(m.z, fmaf(z.z, A.z, Bb.z));
    m.w = fmaxf(m.w, fmaf(z.w, A.w, Bb.w));
  }
  m.x = fmaxf(m.x, 0.f); m.y = fmaxf(m.y, 0.f);
  m.z = fmaxf(m.z, 0.f); m.w = fmaxf(m.w, 0.f);
  ((float4*)outF)[t] = m;                  // max(relu(x)) == relu(max(x))
}

extern "C" void kernel_launch(void* const* d_in, const int* in_sizes, int n_in,
                              void* d_out, int out_size, void* d_ws, size_t ws_size,
                              hipStream_t stream) {
  const float* xyz      = (const float*)d_in[0];
  const float* features = (const float*)d_in[1];
  const float* w0  = (const float*)d_in[2];
  const float* b0  = (const float*)d_in[3];
  const float* g0  = (const float*)d_in[4];
  const float* be0 = (const float*)d_in[5];
  const float* w1  = (const float*)d_in[6];
  const float* b1  = (const float*)d_in[7];
  const float* g1  = (const float*)d_in[8];
  const float* be1 = (const float*)d_in[9];

  char* wp = (char*)d_ws;
  float4* pts4 = (float4*)wp;  wp += (size_t)B*N*sizeof(float4);     // 512 KB
  float4* q4   = (float4*)wp;  wp += (size_t)B*S*sizeof(float4);     // 128 KB
  int*    knn  = (int*)wp;     wp += (size_t)R*sizeof(int);          // 512 KB
  float*  Z    = (float*)wp;   wp += (size_t)R*C*sizeof(float);      // 64 MB
  float*  part = (float*)wp;   wp += (size_t)128*C*2*sizeof(float);  // 128 KB
  float*  AB0  = (float*)wp;   wp += (size_t)2*C*sizeof(float);
  float*  AB1  = (float*)wp;   wp += (size_t)2*C*sizeof(float);

  float* out_xyz  = (float*)d_out;            // [B,S,3]
  float* out_feat = (float*)d_out + B*S*3;    // [B,S,C]

  prep_kernel<<<(B*N)/256, 256, 0, stream>>>(xyz, pts4);
  fps_kernel<<<B, 256, 0, stream>>>(pts4, q4, out_xyz);
  knn_kernel<<<(B*S)/256, 256, 0, stream>>>(pts4, q4, knn);
  gemm0_kernel<<<R/256, 256, 0, stream>>>(pts4, q4, features, knn, w0, b0, Z);
  stats_kernel<<<128, 256, 0, stream>>>(Z, part);
  finalize_kernel<<<1, 128, 0, stream>>>(part, g0, be0, AB0);
  gemm1_kernel<<<R/256, 256, 0, stream>>>(Z, AB0, w1, b1);
  stats_kernel<<<128, 256, 0, stream>>>(Z, part);
  finalize_kernel<<<1, 128, 0, stream>>>(part, g1, be1, AB1);
  maxpool_kernel<<<(B*S*32)/256, 256, 0, stream>>>(Z, AB1, out_feat);
}

// Round 2
// 5167.817 us; speedup vs baseline: 1.1703x; 1.1703x over previous
//
#include <hip/hip_runtime.h>

#define B 4
#define N 8192
#define F 64
#define S 2048
#define K 16
#define C 128
#define R (B*S*K)   // 131072 rows

// ---------- exact-arithmetic helpers (match numpy op order, no fma fusion) ----------
__device__ __forceinline__ float dist2_sub(float ax, float ay, float az,
                                           float bx, float by, float bz) {
#pragma clang fp contract(off)
  float dx = ax - bx, dy = ay - by, dz = az - bz;
  return (dx*dx + dy*dy) + dz*dz;          // ((d0+d1)+d2), separate rounding
}

__device__ __forceinline__ float norm2f(float x, float y, float z) {
#pragma clang fp contract(off)
  return (x*x + y*y) + z*z;
}

__device__ __forceinline__ float knn_d2(float4 q, float4 p) {
#pragma clang fp contract(off)
  float dot = (q.x*p.x + q.y*p.y) + q.z*p.z;
  return (q.w + p.w) - 2.0f*dot;           // (qn+pn) - 2*dot, reference order
}

// ---------- DPP cross-lane (VALU pipe, ~8 cyc/stage vs ~100 for ds_bpermute) ----------
// old=0 => invalid lanes contribute 0: identity-safe for f32-max of nonneg and u32-max.
#define DPP_F(v, ctrl) __int_as_float(__builtin_amdgcn_update_dpp(0, __float_as_int(v), ctrl, 0xf, 0xf, true))
#define DPP_U(v, ctrl) ((unsigned)__builtin_amdgcn_update_dpp(0, (int)(v), ctrl, 0xf, 0xf, true))
__device__ __forceinline__ unsigned umaxu(unsigned a, unsigned b) { return a > b ? a : b; }

// ---------- prep: pad xyz to float4 with |p|^2 in w ----------
__global__ void prep_kernel(const float* __restrict__ xyz, float4* __restrict__ pts4) {
  int i = blockIdx.x*blockDim.x + threadIdx.x;   // B*N
  if (i >= B*N) return;
  float x = xyz[i*3+0], y = xyz[i*3+1], z = xyz[i*3+2];
  pts4[i] = make_float4(x, y, z, norm2f(x, y, z));
}

// ---------- transpose w1 [o][c] -> w1t [c][o] for contiguous scalar weight loads ----------
__global__ void transpose_w1_kernel(const float* __restrict__ w1, float* __restrict__ w1t) {
  int i = blockIdx.x*256 + threadIdx.x;    // C*C = 16384
  int o = i >> 7, c = i & 127;
  w1t[c*C + o] = w1[o*C + c];
}

// ---------- FPS: one block per batch; DPP-based two-phase argmax ----------
__global__ __launch_bounds__(256, 1) void fps_kernel(const float4* __restrict__ pts4,
                                                     float4* __restrict__ q4,
                                                     float* __restrict__ out_xyz) {
  const int b = blockIdx.x;
  const int t = threadIdx.x;
  const int wid = t >> 6;
  const float4* pb = pts4 + b*N;

  float px[32], py[32], pz[32], md[32];
#pragma unroll
  for (int i = 0; i < 32; ++i) {
    float4 v = pb[i*256 + t];              // coalesced; thread owns idx i*256+t
    px[i] = v.x; py[i] = v.y; pz[i] = v.z; md[i] = 1e10f;   // BIG
  }

  __shared__ float    swv[4];
  __shared__ unsigned swi[4];

  const unsigned cb = 0x7FFFFFFFu - (unsigned)t;   // complement base
  int w = 0;                               // reference starts at index 0
  for (int s = 0; ; ++s) {
    w = __builtin_amdgcn_readfirstlane(w);
    float4 pw = pb[w];                     // uniform -> scalar load
    if (t == 0) {
      q4[b*S + s] = pw;
      out_xyz[(b*S + s)*3 + 0] = pw.x;
      out_xyz[(b*S + s)*3 + 1] = pw.y;
      out_xyz[(b*S + s)*3 + 2] = pw.z;
    }
    if (s == S-1) break;

    // phase 1: update min_d, track exact f32 max only
    float bv = 0.0f;                       // min_d >= 0
#pragma unroll
    for (int i = 0; i < 32; ++i) {
      float d = dist2_sub(px[i], py[i], pz[i], pw.x, pw.y, pw.z);
      float m = fminf(md[i], d);
      md[i] = m;
      bv = fmaxf(bv, m);
    }
    // wave max via DPP (lane 63 holds wave result)
    bv = fmaxf(bv, DPP_F(bv, 0x111));
    bv = fmaxf(bv, DPP_F(bv, 0x112));
    bv = fmaxf(bv, DPP_F(bv, 0x114));
    bv = fmaxf(bv, DPP_F(bv, 0x118));
    bv = fmaxf(bv, DPP_F(bv, 0x142));      // row_bcast:15
    bv = fmaxf(bv, DPP_F(bv, 0x143));      // row_bcast:31
    if ((t & 63) == 63) swv[wid] = bv;
    __syncthreads();
    float bm = fmaxf(fmaxf(swv[0], swv[1]), fmaxf(swv[2], swv[3]));  // exact block max

    // phase 2: min index attaining bm == max of complement (parallel tree, no carry chain)
    unsigned wv = 0u;
#pragma unroll
    for (int i = 0; i < 32; ++i) {
      unsigned cand = (md[i] == bm) ? (cb - (unsigned)(i*256)) : 0u;
      wv = umaxu(wv, cand);
    }
    wv = umaxu(wv, DPP_U(wv, 0x111));
    wv = umaxu(wv, DPP_U(wv, 0x112));
    wv = umaxu(wv, DPP_U(wv, 0x114));
    wv = umaxu(wv, DPP_U(wv, 0x118));
    wv = umaxu(wv, DPP_U(wv, 0x142));
    wv = umaxu(wv, DPP_U(wv, 0x143));
    if ((t & 63) == 63) swi[wid] = wv;
    __syncthreads();
    unsigned mm = umaxu(umaxu(swi[0], swi[1]), umaxu(swi[2], swi[3]));
    w = (int)(0x7FFFFFFFu - mm);           // lowest index with md == bm
  }
}

// ---------- KNN: one thread per query, full scan, sorted 16-reg insertion ----------
__global__ __launch_bounds__(256, 1) void knn_kernel(const float4* __restrict__ pts4,
                                                     const float4* __restrict__ q4,
                                                     int* __restrict__ knn) {
  int qi = blockIdx.x*256 + threadIdx.x;   // 0..B*S-1
  int b = qi >> 11;                        // S = 2048
  const float4* pb = pts4 + b*N;
  float4 q = q4[qi];

  float dv[16]; int di[16];
#pragma unroll
  for (int j = 0; j < 16; ++j) { dv[j] = 3.4e38f; di[j] = 0; }

  for (int n = 0; n < N; ++n) {
    float4 p = pb[n];                      // uniform across wave -> scalar load
    float d2 = knn_d2(q, p);
    if (d2 < dv[15]) {                     // strict: incumbent (earlier index) wins ties
#pragma unroll
      for (int j = 15; j >= 1; --j) {
        bool c1 = d2 < dv[j-1];
        bool c2 = d2 < dv[j];
        dv[j] = c1 ? dv[j-1] : (c2 ? d2 : dv[j]);
        di[j] = c1 ? di[j-1] : (c2 ? n  : di[j]);
      }
      if (d2 < dv[0]) { dv[0] = d2; di[0] = n; }
    }
  }
#pragma unroll
  for (int j = 0; j < 16; ++j) knn[qi*16 + j] = di[j];
}

// ---------- GEMM0: gather row (3 xyz-norm + 64 feat) and multiply by w0 [128x67] ----------
__global__ __launch_bounds__(256, 2) void gemm0_kernel(const float4* __restrict__ pts4,
                                                       const float4* __restrict__ q4,
                                                       const float* __restrict__ feat,
                                                       const int* __restrict__ knn,
                                                       const float* __restrict__ w0,
                                                       const float* __restrict__ b0,
                                                       float* __restrict__ Z) {
  int r = blockIdx.x*256 + threadIdx.x;    // 0..R-1
  int bs = r >> 4;                         // b*S + s
  int b  = r >> 15;                        // S*K = 32768 rows per batch
  int p  = knn[r];
  float4 q  = q4[bs];
  float4 pp = pts4[b*N + p];

  float row[67];
  row[0] = pp.x - q.x; row[1] = pp.y - q.y; row[2] = pp.z - q.z;
  const float4* fp = (const float4*)(feat + (size_t)(b*N + p)*F);
#pragma unroll
  for (int i = 0; i < 16; ++i) {
    float4 v = fp[i];
    row[3+4*i] = v.x; row[4+4*i] = v.y; row[5+4*i] = v.z; row[6+4*i] = v.w;
  }

  float* zr = Z + (size_t)r*C;
  for (int og = 0; og < C/4; ++og) {
    float a0 = b0[og*4+0], a1 = b0[og*4+1], a2 = b0[og*4+2], a3 = b0[og*4+3];
    const float* wr = w0 + og*4*67;        // uniform -> scalar loads
#pragma unroll
    for (int c = 0; c < 67; ++c) {
      float x = row[c];
      a0 = fmaf(x, wr[c      ], a0);
      a1 = fmaf(x, wr[67  + c], a1);
      a2 = fmaf(x, wr[134 + c], a2);
      a3 = fmaf(x, wr[201 + c], a3);
    }
    ((float4*)zr)[og] = make_float4(a0, a1, a2, a3);
  }
}

// ---------- per-channel stats partials: sum and sumsq over rows ----------
__global__ void stats_kernel(const float* __restrict__ Z, float* __restrict__ part) {
  int c = threadIdx.x & 127;
  int g = threadIdx.x >> 7;                // 0/1
  int chunk = blockIdx.x*2 + g;            // 0..255
  const int rows = R/256;                  // 512
  const float* zp = Z + (size_t)chunk*rows*C + c;
  float s1 = 0.f, s2 = 0.f;
  for (int j = 0; j < rows; ++j) {
    float v = zp[(size_t)j*C];
    s1 += v;
    s2 = fmaf(v, v, s2);
  }
  __shared__ float sh[2][2][128];
  sh[g][0][c] = s1; sh[g][1][c] = s2;
  __syncthreads();
  if (g == 0) {
    part[(blockIdx.x*128 + c)*2 + 0] = s1 + sh[1][0][c];
    part[(blockIdx.x*128 + c)*2 + 1] = s2 + sh[1][1][c];
  }
}

// ---------- finalize BN: A = gamma*rstd, B = beta - mean*gamma*rstd ----------
__global__ void finalize_kernel(const float* __restrict__ part,
                                const float* __restrict__ gamma,
                                const float* __restrict__ beta,
                                float* __restrict__ AB) {
  int c = threadIdx.x;                     // 128 threads
  float s1 = 0.f, s2 = 0.f;
  for (int i = 0; i < 128; ++i) {
    s1 += part[(i*128 + c)*2 + 0];
    s2 += part[(i*128 + c)*2 + 1];
  }
  const float inv = 1.0f/(float)R;
  float mean = s1*inv;
  float var  = s2*inv - mean*mean;         // biased variance
  float rstd = rsqrtf(var + 1e-5f);
  float a = gamma[c]*rstd;
  AB[c]     = a;
  AB[C + c] = beta[c] - mean*a;
}

// ---------- GEMM1: LDS-tiled (64 rows/block), no register spill, in-place on Z ----------
// Applies BN0+ReLU on load. Weights from w1t [c][o] via wave-uniform scalar loads.
__global__ __launch_bounds__(256, 4) void gemm1_kernel(float* __restrict__ Z,
                                                       const float* __restrict__ AB0,
                                                       const float* __restrict__ w1t,
                                                       const float* __restrict__ b1) {
  __shared__ float hs[64 * 129];           // stride 129: (row+c)%32 banks -> 2-way = free
  const int tid = threadIdx.x;
  const size_t base = (size_t)blockIdx.x * 64;

  // Phase A: load 64 rows x 128, BN0+ReLU -> LDS
  const float4* Z4 = (const float4*)(Z + base * C);
#pragma unroll
  for (int k = 0; k < 8; ++k) {
    int f = tid + k*256;                   // float4 index, 0..2047
    int row = f >> 5, c4 = f & 31;
    float4 v  = Z4[f];
    float4 A  = ((const float4*)AB0)[c4];
    float4 Bb = ((const float4*)AB0)[32 + c4];
    int lb = row*129 + c4*4;
    hs[lb+0] = fmaxf(fmaf(v.x, A.x, Bb.x), 0.f);
    hs[lb+1] = fmaxf(fmaf(v.y, A.y, Bb.y), 0.f);
    hs[lb+2] = fmaxf(fmaf(v.z, A.z, Bb.z), 0.f);
    hs[lb+3] = fmaxf(fmaf(v.w, A.w, Bb.w), 0.f);
  }
  __syncthreads();

  // Phase B: thread (row = tid&63, quarter = tid>>6) computes 32 outputs
  const int row = tid & 63;
  const int qu  = __builtin_amdgcn_readfirstlane(tid >> 6);  // wave-uniform -> s_loads
  const float* wq = w1t + qu*32;           // w1t[c*C + o]
  float acc[32];
#pragma unroll
  for (int o = 0; o < 32; ++o) acc[o] = b1[qu*32 + o];
  const float* hrow = hs + row*129;
  for (int c = 0; c < C; ++c) {
    float x = hrow[c];                     // ds_read_b32, 2-way banked = free
    const float* wr = wq + c*C;            // uniform: s_load_dwordx16 x2
#pragma unroll
    for (int o = 0; o < 32; ++o) acc[o] = fmaf(x, wr[o], acc[o]);
  }
  __syncthreads();                         // all reads of hs done before overwrite

  // stage outputs back through LDS for coalesced float4 stores
#pragma unroll
  for (int o = 0; o < 32; ++o) hs[row*129 + qu*32 + o] = acc[o];
  __syncthreads();
  float4* Zo = (float4*)(Z + base * C);
#pragma unroll
  for (int k = 0; k < 8; ++k) {
    int f = tid + k*256;
    int row2 = f >> 5, c4 = f & 31;
    int lb = row2*129 + c4*4;
    Zo[f] = make_float4(hs[lb+0], hs[lb+1], hs[lb+2], hs[lb+3]);
  }
}

// ---------- maxpool over K with BN1+ReLU fused ----------
__global__ void maxpool_kernel(const float* __restrict__ Z,
                               const float* __restrict__ AB1,
                               float* __restrict__ outF) {
  int t = blockIdx.x*256 + threadIdx.x;    // B*S*32
  int bs = t >> 5, c4 = t & 31;
  const float4* zp = (const float4*)Z + (size_t)bs*K*(C/4) + c4;
  float4 A  = ((const float4*)AB1)[c4];
  float4 Bb = ((const float4*)(AB1 + C))[c4];
  float4 m = make_float4(-3.4e38f, -3.4e38f, -3.4e38f, -3.4e38f);
#pragma unroll
  for (int k = 0; k < K; ++k) {
    float4 z = zp[(size_t)k*(C/4)];
    m.x = fmaxf(m.x, fmaf(z.x, A.x, Bb.x));
    m.y = fmaxf(m.y, fmaf(z.y, A.y, Bb.y));
    m.z = fmaxf(m.z, fmaf(z.z, A.z, Bb.z));
    m.w = fmaxf(m.w, fmaf(z.w, A.w, Bb.w));
  }
  m.x = fmaxf(m.x, 0.f); m.y = fmaxf(m.y, 0.f);
  m.z = fmaxf(m.z, 0.f); m.w = fmaxf(m.w, 0.f);
  ((float4*)outF)[t] = m;                  // max(relu(x)) == relu(max(x))
}

extern "C" void kernel_launch(void* const* d_in, const int* in_sizes, int n_in,
                              void* d_out, int out_size, void* d_ws, size_t ws_size,
                              hipStream_t stream) {
  const float* xyz      = (const float*)d_in[0];
  const float* features = (const float*)d_in[1];
  const float* w0  = (const float*)d_in[2];
  const float* b0  = (const float*)d_in[3];
  const float* g0  = (const float*)d_in[4];
  const float* be0 = (const float*)d_in[5];
  const float* w1  = (const float*)d_in[6];
  const float* b1  = (const float*)d_in[7];
  const float* g1  = (const float*)d_in[8];
  const float* be1 = (const float*)d_in[9];

  char* wp = (char*)d_ws;
  float4* pts4 = (float4*)wp;  wp += (size_t)B*N*sizeof(float4);     // 512 KB
  float4* q4   = (float4*)wp;  wp += (size_t)B*S*sizeof(float4);     // 128 KB
  int*    knn  = (int*)wp;     wp += (size_t)R*sizeof(int);          // 512 KB
  float*  Z    = (float*)wp;   wp += (size_t)R*C*sizeof(float);      // 64 MB
  float*  part = (float*)wp;   wp += (size_t)128*C*2*sizeof(float);  // 128 KB
  float*  AB0  = (float*)wp;   wp += (size_t)2*C*sizeof(float);
  float*  AB1  = (float*)wp;   wp += (size_t)2*C*sizeof(float);
  float*  w1t  = (float*)wp;   wp += (size_t)C*C*sizeof(float);      // 64 KB

  float* out_xyz  = (float*)d_out;            // [B,S,3]
  float* out_feat = (float*)d_out + B*S*3;    // [B,S,C]

  prep_kernel<<<(B*N)/256, 256, 0, stream>>>(xyz, pts4);
  transpose_w1_kernel<<<(C*C)/256, 256, 0, stream>>>(w1, w1t);
  fps_kernel<<<B, 256, 0, stream>>>(pts4, q4, out_xyz);
  knn_kernel<<<(B*S)/256, 256, 0, stream>>>(pts4, q4, knn);
  gemm0_kernel<<<R/256, 256, 0, stream>>>(pts4, q4, features, knn, w0, b0, Z);
  stats_kernel<<<128, 256, 0, stream>>>(Z, part);
  finalize_kernel<<<1, 128, 0, stream>>>(part, g0, be0, AB0);
  gemm1_kernel<<<R/64, 256, 0, stream>>>(Z, AB0, w1t, b1);
  stats_kernel<<<128, 256, 0, stream>>>(Z, part);
  finalize_kernel<<<1, 128, 0, stream>>>(part, g1, be1, AB1);
  maxpool_kernel<<<(B*S*32)/256, 256, 0, stream>>>(Z, AB1, out_feat);
}

// Round 3
// 4085.616 us; speedup vs baseline: 1.4803x; 1.2649x over previous
//
#include <hip/hip_runtime.h>

#define B 4
#define N 8192
#define F 64
#define S 2048
#define K 16
#define C 128
#define R (B*S*K)   // 131072 rows

// ---------- exact-arithmetic helpers (match numpy op order, no fma fusion) ----------
__device__ __forceinline__ float dist2_sub(float ax, float ay, float az,
                                           float bx, float by, float bz) {
#pragma clang fp contract(off)
  float dx = ax - bx, dy = ay - by, dz = az - bz;
  return (dx*dx + dy*dy) + dz*dz;          // ((d0+d1)+d2), separate rounding
}

__device__ __forceinline__ float norm2f(float x, float y, float z) {
#pragma clang fp contract(off)
  return (x*x + y*y) + z*z;
}

__device__ __forceinline__ float knn_d2(float4 q, float4 p) {
#pragma clang fp contract(off)
  float dot = (q.x*p.x + q.y*p.y) + q.z*p.z;
  return (q.w + p.w) - 2.0f*dot;           // (qn+pn) - 2*dot, reference order
}

// ---------- DPP cross-lane (VALU pipe). bound_ctrl=1 -> invalid lanes read 0:
// identity-safe for f32-max of nonneg and u32-max. Pattern HW-verified (round 2 passed).
#define DPP_F(v, ctrl) __int_as_float(__builtin_amdgcn_update_dpp(0, __float_as_int(v), ctrl, 0xf, 0xf, true))
#define DPP_U(v, ctrl) ((unsigned)__builtin_amdgcn_update_dpp(0, (int)(v), ctrl, 0xf, 0xf, true))
__device__ __forceinline__ unsigned umaxu(unsigned a, unsigned b) { return a > b ? a : b; }

#define WAVE_MAX_F(x) do { \
  x = fmaxf(x, DPP_F(x,0x111)); x = fmaxf(x, DPP_F(x,0x112)); \
  x = fmaxf(x, DPP_F(x,0x114)); x = fmaxf(x, DPP_F(x,0x118)); \
  x = fmaxf(x, DPP_F(x,0x142)); x = fmaxf(x, DPP_F(x,0x143)); } while(0)

#define WAVE_MAX_U(x) do { \
  x = umaxu(x, DPP_U(x,0x111)); x = umaxu(x, DPP_U(x,0x112)); \
  x = umaxu(x, DPP_U(x,0x114)); x = umaxu(x, DPP_U(x,0x118)); \
  x = umaxu(x, DPP_U(x,0x142)); x = umaxu(x, DPP_U(x,0x143)); } while(0)

// ---------- prep: pad xyz to float4 with |p|^2 in w ----------
__global__ void prep_kernel(const float* __restrict__ xyz, float4* __restrict__ pts4) {
  int i = blockIdx.x*blockDim.x + threadIdx.x;   // B*N
  if (i >= B*N) return;
  float x = xyz[i*3+0], y = xyz[i*3+1], z = xyz[i*3+2];
  pts4[i] = make_float4(x, y, z, norm2f(x, y, z));
}

// ---------- transpose w1 [o][c] -> w1t [c][o] for contiguous scalar weight loads ----------
__global__ void transpose_w1_kernel(const float* __restrict__ w1, float* __restrict__ w1t) {
  int i = blockIdx.x*256 + threadIdx.x;    // C*C = 16384
  int o = i >> 7, c = i & 127;
  w1t[c*C + o] = w1[o*C + c];
}

// ---------- FPS: one block per batch; single barrier/step; winner coords broadcast
// through LDS (no global load on the critical path) ----------
__global__ __launch_bounds__(256, 1) void fps_kernel(const float4* __restrict__ pts4,
                                                     float4* __restrict__ q4,
                                                     float* __restrict__ out_xyz) {
  const int b = blockIdx.x;
  const int t = threadIdx.x;
  const int wid = t >> 6;
  const float4* pb = pts4 + b*N;

  float px[32], py[32], pz[32], md[32];
#pragma unroll
  for (int i = 0; i < 32; ++i) {
    float4 v = pb[i*256 + t];              // coalesced; thread owns global idx i*256+t
    px[i] = v.x; py[i] = v.y; pz[i] = v.z; md[i] = 1e10f;   // BIG
  }

  __shared__ float    swv[2][4], swx[2][4], swy[2][4], swz[2][4];
  __shared__ unsigned swk[2][4];

  float wx, wy, wz;
  { float4 p0 = pb[0]; wx = p0.x; wy = p0.y; wz = p0.z; }   // reference starts at idx 0
  const unsigned cbt = 0x7FFFFFFFu - (unsigned)t;           // complement base (global idx = i*256+t)

  for (int s = 0; ; ++s) {
    if (t == 0) {
      q4[b*S + s] = make_float4(wx, wy, wz, norm2f(wx, wy, wz));
      out_xyz[(b*S + s)*3 + 0] = wx;
      out_xyz[(b*S + s)*3 + 1] = wy;
      out_xyz[(b*S + s)*3 + 2] = wz;
    }
    if (s == S-1) break;

    // fused: min_d update + per-lane argmax (value, slot, coords); strict > = first-wins
    float bv = -1.0f, bx = 0.f, by = 0.f, bz = 0.f; int bi = 0;
#pragma unroll
    for (int i = 0; i < 32; ++i) {
      float d = dist2_sub(px[i], py[i], pz[i], wx, wy, wz);
      float m = fminf(md[i], d);
      md[i] = m;
      bool g = m > bv;
      bv = g ? m  : bv;
      bi = g ? i  : bi;
      bx = g ? px[i] : bx;
      by = g ? py[i] : by;
      bz = g ? pz[i] : bz;
    }
    // wave max of bv (exact), broadcast via readlane
    float rv = bv;
    WAVE_MAX_F(rv);
    float bwu = __int_as_float(__builtin_amdgcn_readlane(__float_as_int(rv), 63));
    // min global index attaining the wave max == max of complement key (unique nonzero)
    unsigned ki = (bv == bwu) ? (cbt - ((unsigned)bi << 8)) : 0u;
    unsigned km = ki;
    WAVE_MAX_U(km);
    unsigned wk = (unsigned)__builtin_amdgcn_readlane((int)km, 63);

    int par = s & 1;
    if (ki == wk) {                        // exactly one lane per wave
      swv[par][wid] = bv; swk[par][wid] = wk;
      swx[par][wid] = bx; swy[par][wid] = by; swz[par][wid] = bz;
    }
    __syncthreads();                       // single barrier (parity dbuf makes WAR safe)

    float v0 = swv[par][0], v1 = swv[par][1], v2 = swv[par][2], v3 = swv[par][3];
    float bm = fmaxf(fmaxf(v0, v1), fmaxf(v2, v3));          // exact block max
    unsigned c0 = (v0 == bm) ? swk[par][0] : 0u;
    unsigned c1 = (v1 == bm) ? swk[par][1] : 0u;
    unsigned c2 = (v2 == bm) ? swk[par][2] : 0u;
    unsigned c3 = (v3 == bm) ? swk[par][3] : 0u;
    unsigned kb = umaxu(umaxu(c0, c1), umaxu(c2, c3));       // min global idx at bm
    float nx = 0.f, ny = 0.f, nz = 0.f;
#pragma unroll
    for (int j = 0; j < 4; ++j) {
      bool c = (swk[par][j] == kb);        // keys globally unique
      nx = c ? swx[par][j] : nx;
      ny = c ? swy[par][j] : ny;
      nz = c ? swz[par][j] : nz;
    }
    wx = nx; wy = ny; wz = nz;
  }
}

// ---------- KNN: one WAVE per query; per-lane sorted top-16 over 128 points,
// then exact 16-round DPP extraction merge (min d, tie -> min point index) ----------
__global__ __launch_bounds__(256, 4) void knn_kernel(const float4* __restrict__ pts4,
                                                     const float4* __restrict__ q4,
                                                     int* __restrict__ knn) {
  const int gtid = blockIdx.x*256 + threadIdx.x;
  const int wave = gtid >> 6;              // query id, 0..B*S-1
  const int lane = threadIdx.x & 63;
  const int b = wave >> 11;                // S = 2048
  const float4* pb = pts4 + (size_t)b*N;
  float4 q = q4[wave];                     // same addr across wave -> broadcast

  float dv[16]; int di[16];
#pragma unroll
  for (int j = 0; j < 16; ++j) { dv[j] = 3.4e38f; di[j] = 0x7FFFFFFF; }

  // scan: lane owns points n = j*64 + lane (ascending -> within-lane ties keep lower idx)
  for (int j = 0; j < N/64; ++j) {
    int n = j*64 + lane;
    float4 p = pb[n];                      // coalesced global_load_dwordx4
    float d2 = knn_d2(q, p);
    // unconditional predicated insertion (insert prob ~1 for any lane at K=16, 128 pts)
#pragma unroll
    for (int k = 15; k >= 1; --k) {
      bool s1 = d2 < dv[k-1];              // strict: incumbent (earlier idx) wins ties
      bool s2 = d2 < dv[k];
      dv[k] = fmaxf(dv[k-1], fminf(d2, dv[k]));   // med3: sorted-insert value update
      di[k] = s1 ? di[k-1] : (s2 ? n : di[k]);
    }
    bool s0 = d2 < dv[0];
    dv[0] = fminf(d2, dv[0]);
    di[0] = s0 ? n : di[0];
  }

  // merge: 16 extraction rounds over the 64 sorted lane-lists
  int myg = 0;
#pragma unroll 1
  for (int r = 0; r < 16; ++r) {
    // order-preserving u32 key of head distance, complemented: max(mk) == min d (all floats)
    unsigned bits = __float_as_uint(dv[0]);
    unsigned ord  = bits ^ (0x80000000u | (unsigned)(((int)bits) >> 31));
    unsigned mk   = ~ord;
    unsigned m = mk;
    WAVE_MAX_U(m);
    unsigned wm = (unsigned)__builtin_amdgcn_readlane((int)m, 63);
    // tie-break: min point index among heads attaining the min distance
    unsigned ci = (mk == wm) ? ~(unsigned)di[0] : 0u;
    unsigned m2 = ci;
    WAVE_MAX_U(m2);
    unsigned wi = (unsigned)__builtin_amdgcn_readlane((int)m2, 63);
    int g = (int)~wi;                      // winning global point index
    if (lane == r) myg = g;
    // pop winner's head (unique lane), backfill sentinel
    bool win = (mk == wm) && ((unsigned)di[0] == ~wi);
#pragma unroll
    for (int k = 0; k < 15; ++k) {
      dv[k] = win ? dv[k+1] : dv[k];
      di[k] = win ? di[k+1] : di[k];
    }
    dv[15] = win ? 3.4e38f   : dv[15];
    di[15] = win ? 0x7FFFFFFF : di[15];
  }
  if (lane < 16) knn[wave*16 + lane] = myg;   // coalesced 16-wide store
}

// ---------- GEMM0: gather row (3 xyz-norm + 64 feat) and multiply by w0 [128x67] ----------
__global__ __launch_bounds__(256, 2) void gemm0_kernel(const float4* __restrict__ pts4,
                                                       const float4* __restrict__ q4,
                                                       const float* __restrict__ feat,
                                                       const int* __restrict__ knn,
                                                       const float* __restrict__ w0,
                                                       const float* __restrict__ b0,
                                                       float* __restrict__ Z) {
  int r = blockIdx.x*256 + threadIdx.x;    // 0..R-1
  int bs = r >> 4;                         // b*S + s
  int b  = r >> 15;                        // S*K = 32768 rows per batch
  int p  = knn[r];
  float4 q  = q4[bs];
  float4 pp = pts4[b*N + p];

  float row[67];
  row[0] = pp.x - q.x; row[1] = pp.y - q.y; row[2] = pp.z - q.z;
  const float4* fp = (const float4*)(feat + (size_t)(b*N + p)*F);
#pragma unroll
  for (int i = 0; i < 16; ++i) {
    float4 v = fp[i];
    row[3+4*i] = v.x; row[4+4*i] = v.y; row[5+4*i] = v.z; row[6+4*i] = v.w;
  }

  float* zr = Z + (size_t)r*C;
  for (int og = 0; og < C/4; ++og) {
    float a0 = b0[og*4+0], a1 = b0[og*4+1], a2 = b0[og*4+2], a3 = b0[og*4+3];
    const float* wr = w0 + og*4*67;        // uniform -> scalar loads
#pragma unroll
    for (int c = 0; c < 67; ++c) {
      float x = row[c];
      a0 = fmaf(x, wr[c      ], a0);
      a1 = fmaf(x, wr[67  + c], a1);
      a2 = fmaf(x, wr[134 + c], a2);
      a3 = fmaf(x, wr[201 + c], a3);
    }
    ((float4*)zr)[og] = make_float4(a0, a1, a2, a3);
  }
}

// ---------- per-channel stats partials: sum and sumsq over rows ----------
__global__ void stats_kernel(const float* __restrict__ Z, float* __restrict__ part) {
  int c = threadIdx.x & 127;
  int g = threadIdx.x >> 7;                // 0/1
  int chunk = blockIdx.x*2 + g;            // 0..255
  const int rows = R/256;                  // 512
  const float* zp = Z + (size_t)chunk*rows*C + c;
  float s1 = 0.f, s2 = 0.f;
  for (int j = 0; j < rows; ++j) {
    float v = zp[(size_t)j*C];
    s1 += v;
    s2 = fmaf(v, v, s2);
  }
  __shared__ float sh[2][2][128];
  sh[g][0][c] = s1; sh[g][1][c] = s2;
  __syncthreads();
  if (g == 0) {
    part[(blockIdx.x*128 + c)*2 + 0] = s1 + sh[1][0][c];
    part[(blockIdx.x*128 + c)*2 + 1] = s2 + sh[1][1][c];
  }
}

// ---------- finalize BN: A = gamma*rstd, B = beta - mean*gamma*rstd ----------
__global__ void finalize_kernel(const float* __restrict__ part,
                                const float* __restrict__ gamma,
                                const float* __restrict__ beta,
                                float* __restrict__ AB) {
  int c = threadIdx.x;                     // 128 threads
  float s1 = 0.f, s2 = 0.f;
  for (int i = 0; i < 128; ++i) {
    s1 += part[(i*128 + c)*2 + 0];
    s2 += part[(i*128 + c)*2 + 1];
  }
  const float inv = 1.0f/(float)R;
  float mean = s1*inv;
  float var  = s2*inv - mean*mean;         // biased variance
  float rstd = rsqrtf(var + 1e-5f);
  float a = gamma[c]*rstd;
  AB[c]     = a;
  AB[C + c] = beta[c] - mean*a;
}

// ---------- GEMM1: LDS-tiled (64 rows/block), no register spill, in-place on Z ----------
__global__ __launch_bounds__(256, 4) void gemm1_kernel(float* __restrict__ Z,
                                                       const float* __restrict__ AB0,
                                                       const float* __restrict__ w1t,
                                                       const float* __restrict__ b1) {
  __shared__ float hs[64 * 129];           // stride 129: 2-way bank aliasing = free
  const int tid = threadIdx.x;
  const size_t base = (size_t)blockIdx.x * 64;

  const float4* Z4 = (const float4*)(Z + base * C);
#pragma unroll
  for (int k = 0; k < 8; ++k) {
    int f = tid + k*256;                   // float4 index, 0..2047
    int row = f >> 5, c4 = f & 31;
    float4 v  = Z4[f];
    float4 A  = ((const float4*)AB0)[c4];
    float4 Bb = ((const float4*)AB0)[32 + c4];
    int lb = row*129 + c4*4;
    hs[lb+0] = fmaxf(fmaf(v.x, A.x, Bb.x), 0.f);
    hs[lb+1] = fmaxf(fmaf(v.y, A.y, Bb.y), 0.f);
    hs[lb+2] = fmaxf(fmaf(v.z, A.z, Bb.z), 0.f);
    hs[lb+3] = fmaxf(fmaf(v.w, A.w, Bb.w), 0.f);
  }
  __syncthreads();

  const int row = tid & 63;
  const int qu  = __builtin_amdgcn_readfirstlane(tid >> 6);  // wave-uniform -> s_loads
  const float* wq = w1t + qu*32;           // w1t[c*C + o]
  float acc[32];
#pragma unroll
  for (int o = 0; o < 32; ++o) acc[o] = b1[qu*32 + o];
  const float* hrow = hs + row*129;
  for (int c = 0; c < C; ++c) {
    float x = hrow[c];
    const float* wr = wq + c*C;            // uniform: s_load_dwordx16 x2
#pragma unroll
    for (int o = 0; o < 32; ++o) acc[o] = fmaf(x, wr[o], acc[o]);
  }
  __syncthreads();

#pragma unroll
  for (int o = 0; o < 32; ++o) hs[row*129 + qu*32 + o] = acc[o];
  __syncthreads();
  float4* Zo = (float4*)(Z + base * C);
#pragma unroll
  for (int k = 0; k < 8; ++k) {
    int f = tid + k*256;
    int row2 = f >> 5, c4 = f & 31;
    int lb = row2*129 + c4*4;
    Zo[f] = make_float4(hs[lb+0], hs[lb+1], hs[lb+2], hs[lb+3]);
  }
}

// ---------- maxpool over K with BN1+ReLU fused ----------
__global__ void maxpool_kernel(const float* __restrict__ Z,
                               const float* __restrict__ AB1,
                               float* __restrict__ outF) {
  int t = blockIdx.x*256 + threadIdx.x;    // B*S*32
  int bs = t >> 5, c4 = t & 31;
  const float4* zp = (const float4*)Z + (size_t)bs*K*(C/4) + c4;
  float4 A  = ((const float4*)AB1)[c4];
  float4 Bb = ((const float4*)(AB1 + C))[c4];
  float4 m = make_float4(-3.4e38f, -3.4e38f, -3.4e38f, -3.4e38f);
#pragma unroll
  for (int k = 0; k < K; ++k) {
    float4 z = zp[(size_t)k*(C/4)];
    m.x = fmaxf(m.x, fmaf(z.x, A.x, Bb.x));
    m.y = fmaxf(m.y, fmaf(z.y, A.y, Bb.y));
    m.z = fmaxf(m.z, fmaf(z.z, A.z, Bb.z));
    m.w = fmaxf(m.w, fmaf(z.w, A.w, Bb.w));
  }
  m.x = fmaxf(m.x, 0.f); m.y = fmaxf(m.y, 0.f);
  m.z = fmaxf(m.z, 0.f); m.w = fmaxf(m.w, 0.f);
  ((float4*)outF)[t] = m;                  // max(relu(x)) == relu(max(x))
}

extern "C" void kernel_launch(void* const* d_in, const int* in_sizes, int n_in,
                              void* d_out, int out_size, void* d_ws, size_t ws_size,
                              hipStream_t stream) {
  const float* xyz      = (const float*)d_in[0];
  const float* features = (const float*)d_in[1];
  const float* w0  = (const float*)d_in[2];
  const float* b0  = (const float*)d_in[3];
  const float* g0  = (const float*)d_in[4];
  const float* be0 = (const float*)d_in[5];
  const float* w1  = (const float*)d_in[6];
  const float* b1  = (const float*)d_in[7];
  const float* g1  = (const float*)d_in[8];
  const float* be1 = (const float*)d_in[9];

  char* wp = (char*)d_ws;
  float4* pts4 = (float4*)wp;  wp += (size_t)B*N*sizeof(float4);     // 512 KB
  float4* q4   = (float4*)wp;  wp += (size_t)B*S*sizeof(float4);     // 128 KB
  int*    knn  = (int*)wp;     wp += (size_t)R*sizeof(int);          // 512 KB
  float*  Z    = (float*)wp;   wp += (size_t)R*C*sizeof(float);      // 64 MB
  float*  part = (float*)wp;   wp += (size_t)128*C*2*sizeof(float);  // 128 KB
  float*  AB0  = (float*)wp;   wp += (size_t)2*C*sizeof(float);
  float*  AB1  = (float*)wp;   wp += (size_t)2*C*sizeof(float);
  float*  w1t  = (float*)wp;   wp += (size_t)C*C*sizeof(float);      // 64 KB

  float* out_xyz  = (float*)d_out;            // [B,S,3]
  float* out_feat = (float*)d_out + B*S*3;    // [B,S,C]

  prep_kernel<<<(B*N)/256, 256, 0, stream>>>(xyz, pts4);
  transpose_w1_kernel<<<(C*C)/256, 256, 0, stream>>>(w1, w1t);
  fps_kernel<<<B, 256, 0, stream>>>(pts4, q4, out_xyz);
  knn_kernel<<<(B*S*64)/256, 256, 0, stream>>>(pts4, q4, knn);
  gemm0_kernel<<<R/256, 256, 0, stream>>>(pts4, q4, features, knn, w0, b0, Z);
  stats_kernel<<<128, 256, 0, stream>>>(Z, part);
  finalize_kernel<<<1, 128, 0, stream>>>(part, g0, be0, AB0);
  gemm1_kernel<<<R/64, 256, 0, stream>>>(Z, AB0, w1t, b1);
  stats_kernel<<<128, 256, 0, stream>>>(Z, part);
  finalize_kernel<<<1, 128, 0, stream>>>(part, g1, be1, AB1);
  maxpool_kernel<<<(B*S*32)/256, 256, 0, stream>>>(Z, AB1, out_feat);
}

// Round 4
// 2709.893 us; speedup vs baseline: 2.2317x; 1.5077x over previous
//
#include <hip/hip_runtime.h>

#define B 4
#define N 8192
#define F 64
#define S 2048
#define K 16
#define C 128
#define R (B*S*K)   // 131072 rows

// ---------- exact-arithmetic helpers (match numpy op order, no fma fusion) ----------
__device__ __forceinline__ float norm2f(float x, float y, float z) {
#pragma clang fp contract(off)
  return (x*x + y*y) + z*z;
}

__device__ __forceinline__ float knn_d2(float4 q, float4 p) {
#pragma clang fp contract(off)
  float dot = (q.x*p.x + q.y*p.y) + q.z*p.z;
  return (q.w + p.w) - 2.0f*dot;           // (qn+pn) - 2*dot, reference order
}

// ---------- DPP cross-lane (VALU pipe). bound_ctrl=1 -> invalid lanes read 0:
// identity-safe for f32-max of nonneg and u32-max. Pattern HW-verified (rounds 2-3).
#define DPP_F(v, ctrl) __int_as_float(__builtin_amdgcn_update_dpp(0, __float_as_int(v), ctrl, 0xf, 0xf, true))
#define DPP_U(v, ctrl) ((unsigned)__builtin_amdgcn_update_dpp(0, (int)(v), ctrl, 0xf, 0xf, true))
__device__ __forceinline__ unsigned umaxu(unsigned a, unsigned b) { return a > b ? a : b; }

#define WAVE_MAX_F(x) do { \
  x = fmaxf(x, DPP_F(x,0x111)); x = fmaxf(x, DPP_F(x,0x112)); \
  x = fmaxf(x, DPP_F(x,0x114)); x = fmaxf(x, DPP_F(x,0x118)); \
  x = fmaxf(x, DPP_F(x,0x142)); x = fmaxf(x, DPP_F(x,0x143)); } while(0)

#define WAVE_MAX_U(x) do { \
  x = umaxu(x, DPP_U(x,0x111)); x = umaxu(x, DPP_U(x,0x112)); \
  x = umaxu(x, DPP_U(x,0x114)); x = umaxu(x, DPP_U(x,0x118)); \
  x = umaxu(x, DPP_U(x,0x142)); x = umaxu(x, DPP_U(x,0x143)); } while(0)

// ---------- prep: pad xyz to float4 with |p|^2 in w ----------
__global__ void prep_kernel(const float* __restrict__ xyz, float4* __restrict__ pts4) {
  int i = blockIdx.x*blockDim.x + threadIdx.x;   // B*N
  if (i >= B*N) return;
  float x = xyz[i*3+0], y = xyz[i*3+1], z = xyz[i*3+2];
  pts4[i] = make_float4(x, y, z, norm2f(x, y, z));
}

// ---------- transpose w1 [o][c] -> w1t [c][o] for contiguous scalar weight loads ----------
__global__ void transpose_w1_kernel(const float* __restrict__ w1, float* __restrict__ w1t) {
  int i = blockIdx.x*256 + threadIdx.x;    // C*C = 16384
  int o = i >> 7, c = i & 127;
  w1t[c*C + o] = w1[o*C + c];
}

// ---------- FPS: one block per batch. No global traffic in the step loop:
// winners buffered in LDS, flushed coalesced at the end. Single barrier/step.
// float2-paired distance math (SLP -> v_pk_*_f32; per-point rounding identical). ----------
__global__ __launch_bounds__(256, 1) void fps_kernel(const float4* __restrict__ pts4,
                                                     float4* __restrict__ q4,
                                                     float* __restrict__ out_xyz) {
  const int b = blockIdx.x;
  const int t = threadIdx.x;
  const int wid = t >> 6;
  const float4* pb = pts4 + b*N;

  // thread t owns points i*256+t, i=0..31, paired (2j, 2j+1) in float2 lanes (x=even i)
  float2 px[16], py[16], pz[16], md[16];
#pragma unroll
  for (int j = 0; j < 16; ++j) {
    float4 v0 = pb[(2*j  )*256 + t];       // coalesced
    float4 v1 = pb[(2*j+1)*256 + t];
    px[j] = make_float2(v0.x, v1.x);
    py[j] = make_float2(v0.y, v1.y);
    pz[j] = make_float2(v0.z, v1.z);
    md[j] = make_float2(1e10f, 1e10f);     // BIG
  }

  __shared__ float4   seq[S];              // 32 KB winner buffer
  __shared__ float    swv[2][4];
  __shared__ unsigned swk[2][4];

  float wx, wy, wz;
  { float4 p0 = pb[0]; wx = p0.x; wy = p0.y; wz = p0.z; }  // reference starts at idx 0
  const unsigned cbt = 0x7FFFFFFFu - (unsigned)t;          // complement of global idx base

  for (int s = 0; ; ++s) {
    if (t == 0) seq[s] = make_float4(wx, wy, wz, 0.f);     // ds_write_b128, fast drain
    if (s == S-1) break;

    // min_d update + per-lane argmax (value, slot). strict > = first(lowest slot) wins.
    float bv = -1.0f; int bi = 0;
#pragma unroll
    for (int j = 0; j < 16; ++j) {
#pragma clang fp contract(off)
      float dx0 = px[j].x - wx, dx1 = px[j].y - wx;
      float dy0 = py[j].x - wy, dy1 = py[j].y - wy;
      float dz0 = pz[j].x - wz, dz1 = pz[j].y - wz;
      float d0 = (dx0*dx0 + dy0*dy0) + dz0*dz0;            // ((x+y)+z), matches np
      float d1 = (dx1*dx1 + dy1*dy1) + dz1*dz1;
      float m0 = fminf(md[j].x, d0);
      float m1 = fminf(md[j].y, d1);
      md[j] = make_float2(m0, m1);
      bool g0 = m0 > bv;
      bv = g0 ? m0 : bv;  bi = g0 ? (2*j)   : bi;
      bool g1 = m1 > bv;
      bv = g1 ? m1 : bv;  bi = g1 ? (2*j+1) : bi;
    }
    // wave-exact max, then min-global-index key among lanes attaining it
    float rv = bv;
    WAVE_MAX_F(rv);
    float bwu = __int_as_float(__builtin_amdgcn_readlane(__float_as_int(rv), 63));
    unsigned ki = (bv == bwu) ? (cbt - ((unsigned)bi << 8)) : 0u;  // 0x7FFFFFFF - (bi*256+t)
    unsigned km = ki;
    WAVE_MAX_U(km);

    int par = s & 1;
    if ((t & 63) == 63) { swv[par][wid] = rv; swk[par][wid] = km; }
    __syncthreads();                       // only lgkm to drain: cheap

    float v0 = swv[par][0], v1 = swv[par][1], v2 = swv[par][2], v3 = swv[par][3];
    float bm = fmaxf(fmaxf(v0, v1), fmaxf(v2, v3));        // exact block max
    unsigned c0 = (v0 == bm) ? swk[par][0] : 0u;
    unsigned c1 = (v1 == bm) ? swk[par][1] : 0u;
    unsigned c2 = (v2 == bm) ? swk[par][2] : 0u;
    unsigned c3 = (v3 == bm) ? swk[par][3] : 0u;
    unsigned kb = umaxu(umaxu(c0, c1), umaxu(c2, c3));     // min global idx at bm
    int w = __builtin_amdgcn_readfirstlane((int)(0x7FFFFFFFu - kb));
    float4 pw = pb[w];                     // wave-uniform -> s_load (L2 ~250 cyc)
    wx = pw.x; wy = pw.y; wz = pw.z;
  }

  __syncthreads();                         // seq complete
#pragma unroll
  for (int i = t; i < S; i += 256) {
    float4 v = seq[i];
    q4[b*S + i] = make_float4(v.x, v.y, v.z, norm2f(v.x, v.y, v.z));
    out_xyz[(b*S + i)*3 + 0] = v.x;
    out_xyz[(b*S + i)*3 + 1] = v.y;
    out_xyz[(b*S + i)*3 + 2] = v.z;
  }
}

// ---------- KNN: one WAVE per query; per-lane sorted top-16 over 128 points,
// then exact 16-round DPP extraction merge (min d, tie -> min point index) ----------
__global__ __launch_bounds__(256, 4) void knn_kernel(const float4* __restrict__ pts4,
                                                     const float4* __restrict__ q4,
                                                     int* __restrict__ knn) {
  const int gtid = blockIdx.x*256 + threadIdx.x;
  const int wave = gtid >> 6;              // query id, 0..B*S-1
  const int lane = threadIdx.x & 63;
  const int b = wave >> 11;                // S = 2048
  const float4* pb = pts4 + (size_t)b*N;
  float4 q = q4[wave];                     // same addr across wave -> broadcast

  float dv[16]; int di[16];
#pragma unroll
  for (int j = 0; j < 16; ++j) { dv[j] = 3.4e38f; di[j] = 0x7FFFFFFF; }

  // scan: lane owns points n = j*64 + lane (ascending -> within-lane ties keep lower idx)
  for (int j = 0; j < N/64; ++j) {
    int n = j*64 + lane;
    float4 p = pb[n];                      // coalesced global_load_dwordx4
    float d2 = knn_d2(q, p);
#pragma unroll
    for (int k = 15; k >= 1; --k) {
      bool s1 = d2 < dv[k-1];              // strict: incumbent (earlier idx) wins ties
      bool s2 = d2 < dv[k];
      dv[k] = fmaxf(dv[k-1], fminf(d2, dv[k]));   // med3: sorted-insert value update
      di[k] = s1 ? di[k-1] : (s2 ? n : di[k]);
    }
    bool s0 = d2 < dv[0];
    dv[0] = fminf(d2, dv[0]);
    di[0] = s0 ? n : di[0];
  }

  // merge: 16 extraction rounds over the 64 sorted lane-lists
  int myg = 0;
#pragma unroll 1
  for (int r = 0; r < 16; ++r) {
    unsigned bits = __float_as_uint(dv[0]);
    unsigned ord  = bits ^ (0x80000000u | (unsigned)(((int)bits) >> 31));
    unsigned mk   = ~ord;                  // max(mk) == min distance (total order)
    unsigned m = mk;
    WAVE_MAX_U(m);
    unsigned wm = (unsigned)__builtin_amdgcn_readlane((int)m, 63);
    unsigned ci = (mk == wm) ? ~(unsigned)di[0] : 0u;
    unsigned m2 = ci;
    WAVE_MAX_U(m2);
    unsigned wi = (unsigned)__builtin_amdgcn_readlane((int)m2, 63);
    int g = (int)~wi;                      // winning global point index
    if (lane == r) myg = g;
    bool win = (mk == wm) && ((unsigned)di[0] == ~wi);
#pragma unroll
    for (int k = 0; k < 15; ++k) {
      dv[k] = win ? dv[k+1] : dv[k];
      di[k] = win ? di[k+1] : di[k];
    }
    dv[15] = win ? 3.4e38f    : dv[15];
    di[15] = win ? 0x7FFFFFFF : di[15];
  }
  if (lane < 16) knn[wave*16 + lane] = myg;   // coalesced 16-wide store
}

// ---------- GEMM0: gather row (3 xyz-norm + 64 feat) and multiply by w0 [128x67] ----------
__global__ __launch_bounds__(256, 2) void gemm0_kernel(const float4* __restrict__ pts4,
                                                       const float4* __restrict__ q4,
                                                       const float* __restrict__ feat,
                                                       const int* __restrict__ knn,
                                                       const float* __restrict__ w0,
                                                       const float* __restrict__ b0,
                                                       float* __restrict__ Z) {
  int r = blockIdx.x*256 + threadIdx.x;    // 0..R-1
  int bs = r >> 4;                         // b*S + s
  int b  = r >> 15;                        // S*K = 32768 rows per batch
  int p  = knn[r];
  float4 q  = q4[bs];
  float4 pp = pts4[b*N + p];

  float row[67];
  row[0] = pp.x - q.x; row[1] = pp.y - q.y; row[2] = pp.z - q.z;
  const float4* fp = (const float4*)(feat + (size_t)(b*N + p)*F);
#pragma unroll
  for (int i = 0; i < 16; ++i) {
    float4 v = fp[i];
    row[3+4*i] = v.x; row[4+4*i] = v.y; row[5+4*i] = v.z; row[6+4*i] = v.w;
  }

  float* zr = Z + (size_t)r*C;
  for (int og = 0; og < C/4; ++og) {
    float a0 = b0[og*4+0], a1 = b0[og*4+1], a2 = b0[og*4+2], a3 = b0[og*4+3];
    const float* wr = w0 + og*4*67;        // uniform -> scalar loads
#pragma unroll
    for (int c = 0; c < 67; ++c) {
      float x = row[c];
      a0 = fmaf(x, wr[c      ], a0);
      a1 = fmaf(x, wr[67  + c], a1);
      a2 = fmaf(x, wr[134 + c], a2);
      a3 = fmaf(x, wr[201 + c], a3);
    }
    ((float4*)zr)[og] = make_float4(a0, a1, a2, a3);
  }
}

// ---------- per-channel stats partials: sum and sumsq over rows ----------
__global__ void stats_kernel(const float* __restrict__ Z, float* __restrict__ part) {
  int c = threadIdx.x & 127;
  int g = threadIdx.x >> 7;                // 0/1
  int chunk = blockIdx.x*2 + g;            // 0..255
  const int rows = R/256;                  // 512
  const float* zp = Z + (size_t)chunk*rows*C + c;
  float s1 = 0.f, s2 = 0.f;
  for (int j = 0; j < rows; ++j) {
    float v = zp[(size_t)j*C];
    s1 += v;
    s2 = fmaf(v, v, s2);
  }
  __shared__ float sh[2][2][128];
  sh[g][0][c] = s1; sh[g][1][c] = s2;
  __syncthreads();
  if (g == 0) {
    part[(blockIdx.x*128 + c)*2 + 0] = s1 + sh[1][0][c];
    part[(blockIdx.x*128 + c)*2 + 1] = s2 + sh[1][1][c];
  }
}

// ---------- finalize BN: A = gamma*rstd, B = beta - mean*gamma*rstd ----------
__global__ void finalize_kernel(const float* __restrict__ part,
                                const float* __restrict__ gamma,
                                const float* __restrict__ beta,
                                float* __restrict__ AB) {
  int c = threadIdx.x;                     // 128 threads
  float s1 = 0.f, s2 = 0.f;
  for (int i = 0; i < 128; ++i) {
    s1 += part[(i*128 + c)*2 + 0];
    s2 += part[(i*128 + c)*2 + 1];
  }
  const float inv = 1.0f/(float)R;
  float mean = s1*inv;
  float var  = s2*inv - mean*mean;         // biased variance
  float rstd = rsqrtf(var + 1e-5f);
  float a = gamma[c]*rstd;
  AB[c]     = a;
  AB[C + c] = beta[c] - mean*a;
}

// ---------- GEMM1: LDS-tiled (64 rows/block), no register spill, in-place on Z ----------
__global__ __launch_bounds__(256, 4) void gemm1_kernel(float* __restrict__ Z,
                                                       const float* __restrict__ AB0,
                                                       const float* __restrict__ w1t,
                                                       const float* __restrict__ b1) {
  __shared__ float hs[64 * 129];           // stride 129: 2-way bank aliasing = free
  const int tid = threadIdx.x;
  const size_t base = (size_t)blockIdx.x * 64;

  const float4* Z4 = (const float4*)(Z + base * C);
#pragma unroll
  for (int k = 0; k < 8; ++k) {
    int f = tid + k*256;                   // float4 index, 0..2047
    int row = f >> 5, c4 = f & 31;
    float4 v  = Z4[f];
    float4 A  = ((const float4*)AB0)[c4];
    float4 Bb = ((const float4*)AB0)[32 + c4];
    int lb = row*129 + c4*4;
    hs[lb+0] = fmaxf(fmaf(v.x, A.x, Bb.x), 0.f);
    hs[lb+1] = fmaxf(fmaf(v.y, A.y, Bb.y), 0.f);
    hs[lb+2] = fmaxf(fmaf(v.z, A.z, Bb.z), 0.f);
    hs[lb+3] = fmaxf(fmaf(v.w, A.w, Bb.w), 0.f);
  }
  __syncthreads();

  const int row = tid & 63;
  const int qu  = __builtin_amdgcn_readfirstlane(tid >> 6);  // wave-uniform -> s_loads
  const float* wq = w1t + qu*32;           // w1t[c*C + o]
  float acc[32];
#pragma unroll
  for (int o = 0; o < 32; ++o) acc[o] = b1[qu*32 + o];
  const float* hrow = hs + row*129;
  for (int c = 0; c < C; ++c) {
    float x = hrow[c];
    const float* wr = wq + c*C;            // uniform: s_load_dwordx16 x2
#pragma unroll
    for (int o = 0; o < 32; ++o) acc[o] = fmaf(x, wr[o], acc[o]);
  }
  __syncthreads();

#pragma unroll
  for (int o = 0; o < 32; ++o) hs[row*129 + qu*32 + o] = acc[o];
  __syncthreads();
  float4* Zo = (float4*)(Z + base * C);
#pragma unroll
  for (int k = 0; k < 8; ++k) {
    int f = tid + k*256;
    int row2 = f >> 5, c4 = f & 31;
    int lb = row2*129 + c4*4;
    Zo[f] = make_float4(hs[lb+0], hs[lb+1], hs[lb+2], hs[lb+3]);
  }
}

// ---------- maxpool over K with BN1+ReLU fused ----------
__global__ void maxpool_kernel(const float* __restrict__ Z,
                               const float* __restrict__ AB1,
                               float* __restrict__ outF) {
  int t = blockIdx.x*256 + threadIdx.x;    // B*S*32
  int bs = t >> 5, c4 = t & 31;
  const float4* zp = (const float4*)Z + (size_t)bs*K*(C/4) + c4;
  float4 A  = ((const float4*)AB1)[c4];
  float4 Bb = ((const float4*)(AB1 + C))[c4];
  float4 m = make_float4(-3.4e38f, -3.4e38f, -3.4e38f, -3.4e38f);
#pragma unroll
  for (int k = 0; k < K; ++k) {
    float4 z = zp[(size_t)k*(C/4)];
    m.x = fmaxf(m.x, fmaf(z.x, A.x, Bb.x));
    m.y = fmaxf(m.y, fmaf(z.y, A.y, Bb.y));
    m.z = fmaxf(m.z, fmaf(z.z, A.z, Bb.z));
    m.w = fmaxf(m.w, fmaf(z.w, A.w, Bb.w));
  }
  m.x = fmaxf(m.x, 0.f); m.y = fmaxf(m.y, 0.f);
  m.z = fmaxf(m.z, 0.f); m.w = fmaxf(m.w, 0.f);
  ((float4*)outF)[t] = m;                  // max(relu(x)) == relu(max(x))
}

extern "C" void kernel_launch(void* const* d_in, const int* in_sizes, int n_in,
                              void* d_out, int out_size, void* d_ws, size_t ws_size,
                              hipStream_t stream) {
  const float* xyz      = (const float*)d_in[0];
  const float* features = (const float*)d_in[1];
  const float* w0  = (const float*)d_in[2];
  const float* b0  = (const float*)d_in[3];
  const float* g0  = (const float*)d_in[4];
  const float* be0 = (const float*)d_in[5];
  const float* w1  = (const float*)d_in[6];
  const float* b1  = (const float*)d_in[7];
  const float* g1  = (const float*)d_in[8];
  const float* be1 = (const float*)d_in[9];

  char* wp = (char*)d_ws;
  float4* pts4 = (float4*)wp;  wp += (size_t)B*N*sizeof(float4);     // 512 KB
  float4* q4   = (float4*)wp;  wp += (size_t)B*S*sizeof(float4);     // 128 KB
  int*    knn  = (int*)wp;     wp += (size_t)R*sizeof(int);          // 512 KB
  float*  Z    = (float*)wp;   wp += (size_t)R*C*sizeof(float);      // 64 MB
  float*  part = (float*)wp;   wp += (size_t)128*C*2*sizeof(float);  // 128 KB
  float*  AB0  = (float*)wp;   wp += (size_t)2*C*sizeof(float);
  float*  AB1  = (float*)wp;   wp += (size_t)2*C*sizeof(float);
  float*  w1t  = (float*)wp;   wp += (size_t)C*C*sizeof(float);      // 64 KB

  float* out_xyz  = (float*)d_out;            // [B,S,3]
  float* out_feat = (float*)d_out + B*S*3;    // [B,S,C]

  prep_kernel<<<(B*N)/256, 256, 0, stream>>>(xyz, pts4);
  transpose_w1_kernel<<<(C*C)/256, 256, 0, stream>>>(w1, w1t);
  fps_kernel<<<B, 256, 0, stream>>>(pts4, q4, out_xyz);
  knn_kernel<<<(B*S*64)/256, 256, 0, stream>>>(pts4, q4, knn);
  gemm0_kernel<<<R/256, 256, 0, stream>>>(pts4, q4, features, knn, w0, b0, Z);
  stats_kernel<<<128, 256, 0, stream>>>(Z, part);
  finalize_kernel<<<1, 128, 0, stream>>>(part, g0, be0, AB0);
  gemm1_kernel<<<R/64, 256, 0, stream>>>(Z, AB0, w1t, b1);
  stats_kernel<<<128, 256, 0, stream>>>(Z, part);
  finalize_kernel<<<1, 128, 0, stream>>>(part, g1, be1, AB1);
  maxpool_kernel<<<(B*S*32)/256, 256, 0, stream>>>(Z, AB1, out_feat);
}

// Round 5
// 2585.013 us; speedup vs baseline: 2.3396x; 1.0483x over previous
//
#include <hip/hip_runtime.h>

#define B 4
#define N 8192
#define F 64
#define S 2048
#define K 16
#define C 128
#define R (B*S*K)   // 131072 rows

// ---------- exact-arithmetic helpers (match numpy op order, no fma fusion) ----------
__device__ __forceinline__ float norm2f(float x, float y, float z) {
#pragma clang fp contract(off)
  return (x*x + y*y) + z*z;
}

__device__ __forceinline__ float knn_d2(float4 q, float4 p) {
#pragma clang fp contract(off)
  float dot = (q.x*p.x + q.y*p.y) + q.z*p.z;
  return (q.w + p.w) - 2.0f*dot;           // (qn+pn) - 2*dot, reference order
}

// opaque def: forbids rematerialization/LICM of the loaded value -> stays in a VGPR
__device__ __forceinline__ void pinf(float& v) { asm volatile("" : "+v"(v)); }

// ---------- DPP cross-lane (VALU pipe). bound_ctrl=1 -> invalid lanes read 0:
// identity-safe for f32-max of nonneg and u32-max. Pattern HW-verified (rounds 2-4).
#define DPP_F(v, ctrl) __int_as_float(__builtin_amdgcn_update_dpp(0, __float_as_int(v), ctrl, 0xf, 0xf, true))
#define DPP_U(v, ctrl) ((unsigned)__builtin_amdgcn_update_dpp(0, (int)(v), ctrl, 0xf, 0xf, true))
__device__ __forceinline__ unsigned umaxu(unsigned a, unsigned b) { return a > b ? a : b; }

#define WAVE_MAX_F(x) do { \
  x = fmaxf(x, DPP_F(x,0x111)); x = fmaxf(x, DPP_F(x,0x112)); \
  x = fmaxf(x, DPP_F(x,0x114)); x = fmaxf(x, DPP_F(x,0x118)); \
  x = fmaxf(x, DPP_F(x,0x142)); x = fmaxf(x, DPP_F(x,0x143)); } while(0)

#define WAVE_MAX_U(x) do { \
  x = umaxu(x, DPP_U(x,0x111)); x = umaxu(x, DPP_U(x,0x112)); \
  x = umaxu(x, DPP_U(x,0x114)); x = umaxu(x, DPP_U(x,0x118)); \
  x = umaxu(x, DPP_U(x,0x142)); x = umaxu(x, DPP_U(x,0x143)); } while(0)

// ---------- prep: pad xyz to float4 with |p|^2 in w ----------
__global__ void prep_kernel(const float* __restrict__ xyz, float4* __restrict__ pts4) {
  int i = blockIdx.x*blockDim.x + threadIdx.x;   // B*N
  if (i >= B*N) return;
  float x = xyz[i*3+0], y = xyz[i*3+1], z = xyz[i*3+2];
  pts4[i] = make_float4(x, y, z, norm2f(x, y, z));
}

// ---------- transpose w1 [o][c] -> w1t [c][o] for contiguous scalar weight loads ----------
__global__ void transpose_w1_kernel(const float* __restrict__ w1, float* __restrict__ w1t) {
  int i = blockIdx.x*256 + threadIdx.x;    // C*C = 16384
  int o = i >> 7, c = i & 127;
  w1t[c*C + o] = w1[o*C + c];
}

// ---------- FPS: one block per batch. Points pinned in VGPRs (no per-step reload);
// winner coords from LDS point cache; winners buffered in LDS, flushed at end. ----------
__global__ __launch_bounds__(256, 1) void fps_kernel(const float4* __restrict__ pts4,
                                                     float4* __restrict__ q4,
                                                     float* __restrict__ out_xyz) {
  const int b = blockIdx.x;
  const int t = threadIdx.x;
  const int wid = t >> 6;
  const float4* pb = pts4 + b*N;

  __shared__ float cx[N], cy[N], cz[N];    // 96 KB point cache (winner lookup)
  __shared__ float sqx[S], sqy[S], sqz[S]; // 24 KB winner sequence
  __shared__ float    swv[2][4];
  __shared__ unsigned swk[2][4];

  // thread t owns points i*256+t, i=0..31, paired (2j, 2j+1); pinned in VGPRs
  float2 px[16], py[16], pz[16], md[16];
#pragma unroll
  for (int j = 0; j < 16; ++j) {
    int i0 = (2*j)*256 + t, i1 = (2*j+1)*256 + t;
    float4 v0 = pb[i0];                    // coalesced
    float4 v1 = pb[i1];
    cx[i0] = v0.x; cy[i0] = v0.y; cz[i0] = v0.z;
    cx[i1] = v1.x; cy[i1] = v1.y; cz[i1] = v1.z;
    px[j] = make_float2(v0.x, v1.x);
    py[j] = make_float2(v0.y, v1.y);
    pz[j] = make_float2(v0.z, v1.z);
    pinf(px[j].x); pinf(px[j].y);
    pinf(py[j].x); pinf(py[j].y);
    pinf(pz[j].x); pinf(pz[j].y);
    md[j] = make_float2(1e10f, 1e10f);     // BIG
  }

  float wx, wy, wz;
  { float4 p0 = pb[0]; wx = p0.x; wy = p0.y; wz = p0.z; }  // reference starts at idx 0
  const unsigned cbt = 0x7FFFFFFFu - (unsigned)t;          // complement of global idx base

  for (int s = 0; ; ++s) {
    if (t == 0) { sqx[s] = wx; sqy[s] = wy; sqz[s] = wz; }
    if (s == S-1) break;

    // min_d update + per-lane argmax (value, slot). strict > = first(lowest slot) wins.
    float bv = -1.0f; int bi = 0;
#pragma unroll
    for (int j = 0; j < 16; ++j) {
#pragma clang fp contract(off)
      float dx0 = px[j].x - wx, dx1 = px[j].y - wx;
      float dy0 = py[j].x - wy, dy1 = py[j].y - wy;
      float dz0 = pz[j].x - wz, dz1 = pz[j].y - wz;
      float d0 = (dx0*dx0 + dy0*dy0) + dz0*dz0;            // ((x+y)+z), matches np
      float d1 = (dx1*dx1 + dy1*dy1) + dz1*dz1;
      float m0 = fminf(md[j].x, d0);
      float m1 = fminf(md[j].y, d1);
      md[j] = make_float2(m0, m1);
      bool g0 = m0 > bv;
      bv = g0 ? m0 : bv;  bi = g0 ? (2*j)   : bi;
      bool g1 = m1 > bv;
      bv = g1 ? m1 : bv;  bi = g1 ? (2*j+1) : bi;
    }
    // wave-exact max, then min-global-index key among lanes attaining it
    float rv = bv;
    WAVE_MAX_F(rv);
    float bwu = __int_as_float(__builtin_amdgcn_readlane(__float_as_int(rv), 63));
    unsigned ki = (bv == bwu) ? (cbt - ((unsigned)bi << 8)) : 0u;  // 0x7FFFFFFF - (bi*256+t)
    unsigned km = ki;
    WAVE_MAX_U(km);

    int par = s & 1;
    if ((t & 63) == 63) { swv[par][wid] = rv; swk[par][wid] = km; }
    __syncthreads();                       // only lgkm to drain: cheap

    float v0 = swv[par][0], v1 = swv[par][1], v2 = swv[par][2], v3 = swv[par][3];
    float bm = fmaxf(fmaxf(v0, v1), fmaxf(v2, v3));        // exact block max
    unsigned c0 = (v0 == bm) ? swk[par][0] : 0u;
    unsigned c1 = (v1 == bm) ? swk[par][1] : 0u;
    unsigned c2 = (v2 == bm) ? swk[par][2] : 0u;
    unsigned c3 = (v3 == bm) ? swk[par][3] : 0u;
    unsigned kb = umaxu(umaxu(c0, c1), umaxu(c2, c3));     // min global idx at bm
    int w = (int)(0x7FFFFFFFu - kb);
    wx = cx[w]; wy = cy[w]; wz = cz[w];    // same-address LDS broadcast (~120 cyc)
  }

  __syncthreads();                         // seq complete
#pragma unroll
  for (int i = t; i < S; i += 256) {
    float x = sqx[i], y = sqy[i], z = sqz[i];
    q4[b*S + i] = make_float4(x, y, z, norm2f(x, y, z));
    out_xyz[(b*S + i)*3 + 0] = x;
    out_xyz[(b*S + i)*3 + 1] = y;
    out_xyz[(b*S + i)*3 + 2] = z;
  }
}

// ---------- KNN: one WAVE per query; per-lane sorted top-16 over 128 points,
// then exact 16-round DPP extraction merge (min d, tie -> min point index) ----------
__global__ __launch_bounds__(256, 4) void knn_kernel(const float4* __restrict__ pts4,
                                                     const float4* __restrict__ q4,
                                                     int* __restrict__ knn) {
  const int gtid = blockIdx.x*256 + threadIdx.x;
  const int wave = gtid >> 6;              // query id, 0..B*S-1
  const int lane = threadIdx.x & 63;
  const int b = wave >> 11;                // S = 2048
  const float4* pb = pts4 + (size_t)b*N;
  float4 q = q4[wave];                     // same addr across wave -> broadcast

  float dv[16]; int di[16];
#pragma unroll
  for (int j = 0; j < 16; ++j) { dv[j] = 3.4e38f; di[j] = 0x7FFFFFFF; }

  // scan: lane owns points n = j*64 + lane (ascending -> within-lane ties keep lower idx)
  for (int j = 0; j < N/64; ++j) {
    int n = j*64 + lane;
    float4 p = pb[n];                      // coalesced global_load_dwordx4
    float d2 = knn_d2(q, p);
#pragma unroll
    for (int k = 15; k >= 1; --k) {
      bool s1 = d2 < dv[k-1];              // strict: incumbent (earlier idx) wins ties
      bool s2 = d2 < dv[k];
      dv[k] = fmaxf(dv[k-1], fminf(d2, dv[k]));   // med3: sorted-insert value update
      di[k] = s1 ? di[k-1] : (s2 ? n : di[k]);
    }
    bool s0 = d2 < dv[0];
    dv[0] = fminf(d2, dv[0]);
    di[0] = s0 ? n : di[0];
  }

  // merge: 16 extraction rounds over the 64 sorted lane-lists
  int myg = 0;
#pragma unroll 1
  for (int r = 0; r < 16; ++r) {
    unsigned bits = __float_as_uint(dv[0]);
    unsigned ord  = bits ^ (0x80000000u | (unsigned)(((int)bits) >> 31));
    unsigned mk   = ~ord;                  // max(mk) == min distance (total order)
    unsigned m = mk;
    WAVE_MAX_U(m);
    unsigned wm = (unsigned)__builtin_amdgcn_readlane((int)m, 63);
    unsigned ci = (mk == wm) ? ~(unsigned)di[0] : 0u;
    unsigned m2 = ci;
    WAVE_MAX_U(m2);
    unsigned wi = (unsigned)__builtin_amdgcn_readlane((int)m2, 63);
    int g = (int)~wi;                      // winning global point index
    if (lane == r) myg = g;
    bool win = (mk == wm) && ((unsigned)di[0] == ~wi);
#pragma unroll
    for (int k = 0; k < 15; ++k) {
      dv[k] = win ? dv[k+1] : dv[k];
      di[k] = win ? di[k+1] : di[k];
    }
    dv[15] = win ? 3.4e38f    : dv[15];
    di[15] = win ? 0x7FFFFFFF : di[15];
  }
  if (lane < 16) knn[wave*16 + lane] = myg;   // coalesced 16-wide store
}

// ---------- GEMM0: gather row (3 xyz-norm + 64 feat) and multiply by w0 [128x67] ----------
__global__ __launch_bounds__(256, 2) void gemm0_kernel(const float4* __restrict__ pts4,
                                                       const float4* __restrict__ q4,
                                                       const float* __restrict__ feat,
                                                       const int* __restrict__ knn,
                                                       const float* __restrict__ w0,
                                                       const float* __restrict__ b0,
                                                       float* __restrict__ Z) {
  int r = blockIdx.x*256 + threadIdx.x;    // 0..R-1
  int bs = r >> 4;                         // b*S + s
  int b  = r >> 15;                        // S*K = 32768 rows per batch
  int p  = knn[r];
  float4 q  = q4[bs];
  float4 pp = pts4[b*N + p];

  float row[67];
  row[0] = pp.x - q.x; row[1] = pp.y - q.y; row[2] = pp.z - q.z;
  const float4* fp = (const float4*)(feat + (size_t)(b*N + p)*F);
#pragma unroll
  for (int i = 0; i < 16; ++i) {
    float4 v = fp[i];
    row[3+4*i] = v.x; row[4+4*i] = v.y; row[5+4*i] = v.z; row[6+4*i] = v.w;
  }

  float* zr = Z + (size_t)r*C;
  for (int og = 0; og < C/4; ++og) {
    float a0 = b0[og*4+0], a1 = b0[og*4+1], a2 = b0[og*4+2], a3 = b0[og*4+3];
    const float* wr = w0 + og*4*67;        // uniform -> scalar loads
#pragma unroll
    for (int c = 0; c < 67; ++c) {
      float x = row[c];
      a0 = fmaf(x, wr[c      ], a0);
      a1 = fmaf(x, wr[67  + c], a1);
      a2 = fmaf(x, wr[134 + c], a2);
      a3 = fmaf(x, wr[201 + c], a3);
    }
    ((float4*)zr)[og] = make_float4(a0, a1, a2, a3);
  }
}

// ---------- per-channel stats partials: sum and sumsq over rows ----------
__global__ void stats_kernel(const float* __restrict__ Z, float* __restrict__ part) {
  int c = threadIdx.x & 127;
  int g = threadIdx.x >> 7;                // 0/1
  int chunk = blockIdx.x*2 + g;            // 0..255
  const int rows = R/256;                  // 512
  const float* zp = Z + (size_t)chunk*rows*C + c;
  float s1 = 0.f, s2 = 0.f;
  for (int j = 0; j < rows; ++j) {
    float v = zp[(size_t)j*C];
    s1 += v;
    s2 = fmaf(v, v, s2);
  }
  __shared__ float sh[2][2][128];
  sh[g][0][c] = s1; sh[g][1][c] = s2;
  __syncthreads();
  if (g == 0) {
    part[(blockIdx.x*128 + c)*2 + 0] = s1 + sh[1][0][c];
    part[(blockIdx.x*128 + c)*2 + 1] = s2 + sh[1][1][c];
  }
}

// ---------- finalize BN: A = gamma*rstd, B = beta - mean*gamma*rstd ----------
__global__ void finalize_kernel(const float* __restrict__ part,
                                const float* __restrict__ gamma,
                                const float* __restrict__ beta,
                                float* __restrict__ AB) {
  int c = threadIdx.x;                     // 128 threads
  float s1 = 0.f, s2 = 0.f;
  for (int i = 0; i < 128; ++i) {
    s1 += part[(i*128 + c)*2 + 0];
    s2 += part[(i*128 + c)*2 + 1];
  }
  const float inv = 1.0f/(float)R;
  float mean = s1*inv;
  float var  = s2*inv - mean*mean;         // biased variance
  float rstd = rsqrtf(var + 1e-5f);
  float a = gamma[c]*rstd;
  AB[c]     = a;
  AB[C + c] = beta[c] - mean*a;
}

// ---------- GEMM1: LDS-tiled (64 rows/block), no register spill, in-place on Z ----------
__global__ __launch_bounds__(256, 4) void gemm1_kernel(float* __restrict__ Z,
                                                       const float* __restrict__ AB0,
                                                       const float* __restrict__ w1t,
                                                       const float* __restrict__ b1) {
  __shared__ float hs[64 * 129];           // stride 129: 2-way bank aliasing = free
  const int tid = threadIdx.x;
  const size_t base = (size_t)blockIdx.x * 64;

  const float4* Z4 = (const float4*)(Z + base * C);
#pragma unroll
  for (int k = 0; k < 8; ++k) {
    int f = tid + k*256;                   // float4 index, 0..2047
    int row = f >> 5, c4 = f & 31;
    float4 v  = Z4[f];
    float4 A  = ((const float4*)AB0)[c4];
    float4 Bb = ((const float4*)AB0)[32 + c4];
    int lb = row*129 + c4*4;
    hs[lb+0] = fmaxf(fmaf(v.x, A.x, Bb.x), 0.f);
    hs[lb+1] = fmaxf(fmaf(v.y, A.y, Bb.y), 0.f);
    hs[lb+2] = fmaxf(fmaf(v.z, A.z, Bb.z), 0.f);
    hs[lb+3] = fmaxf(fmaf(v.w, A.w, Bb.w), 0.f);
  }
  __syncthreads();

  const int row = tid & 63;
  const int qu  = __builtin_amdgcn_readfirstlane(tid >> 6);  // wave-uniform -> s_loads
  const float* wq = w1t + qu*32;           // w1t[c*C + o]
  float acc[32];
#pragma unroll
  for (int o = 0; o < 32; ++o) acc[o] = b1[qu*32 + o];
  const float* hrow = hs + row*129;
  for (int c = 0; c < C; ++c) {
    float x = hrow[c];
    const float* wr = wq + c*C;            // uniform: s_load_dwordx16 x2
#pragma unroll
    for (int o = 0; o < 32; ++o) acc[o] = fmaf(x, wr[o], acc[o]);
  }
  __syncthreads();

#pragma unroll
  for (int o = 0; o < 32; ++o) hs[row*129 + qu*32 + o] = acc[o];
  __syncthreads();
  float4* Zo = (float4*)(Z + base * C);
#pragma unroll
  for (int k = 0; k < 8; ++k) {
    int f = tid + k*256;
    int row2 = f >> 5, c4 = f & 31;
    int lb = row2*129 + c4*4;
    Zo[f] = make_float4(hs[lb+0], hs[lb+1], hs[lb+2], hs[lb+3]);
  }
}

// ---------- maxpool over K with BN1+ReLU fused ----------
__global__ void maxpool_kernel(const float* __restrict__ Z,
                               const float* __restrict__ AB1,
                               float* __restrict__ outF) {
  int t = blockIdx.x*256 + threadIdx.x;    // B*S*32
  int bs = t >> 5, c4 = t & 31;
  const float4* zp = (const float4*)Z + (size_t)bs*K*(C/4) + c4;
  float4 A  = ((const float4*)AB1)[c4];
  float4 Bb = ((const float4*)(AB1 + C))[c4];
  float4 m = make_float4(-3.4e38f, -3.4e38f, -3.4e38f, -3.4e38f);
#pragma unroll
  for (int k = 0; k < K; ++k) {
    float4 z = zp[(size_t)k*(C/4)];
    m.x = fmaxf(m.x, fmaf(z.x, A.x, Bb.x));
    m.y = fmaxf(m.y, fmaf(z.y, A.y, Bb.y));
    m.z = fmaxf(m.z, fmaf(z.z, A.z, Bb.z));
    m.w = fmaxf(m.w, fmaf(z.w, A.w, Bb.w));
  }
  m.x = fmaxf(m.x, 0.f); m.y = fmaxf(m.y, 0.f);
  m.z = fmaxf(m.z, 0.f); m.w = fmaxf(m.w, 0.f);
  ((float4*)outF)[t] = m;                  // max(relu(x)) == relu(max(x))
}

extern "C" void kernel_launch(void* const* d_in, const int* in_sizes, int n_in,
                              void* d_out, int out_size, void* d_ws, size_t ws_size,
                              hipStream_t stream) {
  const float* xyz      = (const float*)d_in[0];
  const float* features = (const float*)d_in[1];
  const float* w0  = (const float*)d_in[2];
  const float* b0  = (const float*)d_in[3];
  const float* g0  = (const float*)d_in[4];
  const float* be0 = (const float*)d_in[5];
  const float* w1  = (const float*)d_in[6];
  const float* b1  = (const float*)d_in[7];
  const float* g1  = (const float*)d_in[8];
  const float* be1 = (const float*)d_in[9];

  char* wp = (char*)d_ws;
  float4* pts4 = (float4*)wp;  wp += (size_t)B*N*sizeof(float4);     // 512 KB
  float4* q4   = (float4*)wp;  wp += (size_t)B*S*sizeof(float4);     // 128 KB
  int*    knn  = (int*)wp;     wp += (size_t)R*sizeof(int);          // 512 KB
  float*  Z    = (float*)wp;   wp += (size_t)R*C*sizeof(float);      // 64 MB
  float*  part = (float*)wp;   wp += (size_t)128*C*2*sizeof(float);  // 128 KB
  float*  AB0  = (float*)wp;   wp += (size_t)2*C*sizeof(float);
  float*  AB1  = (float*)wp;   wp += (size_t)2*C*sizeof(float);
  float*  w1t  = (float*)wp;   wp += (size_t)C*C*sizeof(float);      // 64 KB

  float* out_xyz  = (float*)d_out;            // [B,S,3]
  float* out_feat = (float*)d_out + B*S*3;    // [B,S,C]

  prep_kernel<<<(B*N)/256, 256, 0, stream>>>(xyz, pts4);
  transpose_w1_kernel<<<(C*C)/256, 256, 0, stream>>>(w1, w1t);
  fps_kernel<<<B, 256, 0, stream>>>(pts4, q4, out_xyz);
  knn_kernel<<<(B*S*64)/256, 256, 0, stream>>>(pts4, q4, knn);
  gemm0_kernel<<<R/256, 256, 0, stream>>>(pts4, q4, features, knn, w0, b0, Z);
  stats_kernel<<<128, 256, 0, stream>>>(Z, part);
  finalize_kernel<<<1, 128, 0, stream>>>(part, g0, be0, AB0);
  gemm1_kernel<<<R/64, 256, 0, stream>>>(Z, AB0, w1t, b1);
  stats_kernel<<<128, 256, 0, stream>>>(Z, part);
  finalize_kernel<<<1, 128, 0, stream>>>(part, g1, be1, AB1);
  maxpool_kernel<<<(B*S*32)/256, 256, 0, stream>>>(Z, AB1, out_feat);
}